// Round 9
// baseline (299.843 us; speedup 1.0000x reference)
//
#include <hip/hip_runtime.h>
#include <math.h>

typedef unsigned short u16;
typedef unsigned int u32;

#define Bb   16
#define Hh   8
#define KD   32
#define DV   128
#define DIM  512
#define Nn   1024
#define OQKV 192
// SCALE * log2(e): QK logits in log2-domain; softmax exp -> v_exp_f32 (2^x)
#define SCALE2 0.25503490221320355f

typedef short bf16x8 __attribute__((ext_vector_type(8)));   // 4 VGPRs = 8 bf16
typedef float f32x16 __attribute__((ext_vector_type(16)));  // 32x32 C/D frag

#define MFMA32(a, b, c) __builtin_amdgcn_mfma_f32_32x32x16_bf16(a, b, c, 0, 0, 0)

__device__ __forceinline__ float fexp2(float x) {
#if __has_builtin(__builtin_amdgcn_exp2f)
  return __builtin_amdgcn_exp2f(x);
#else
  return exp2f(x);
#endif
}

__device__ __forceinline__ u16 f2bf_rn(float f) {
  return (u16)((__float_as_uint(f) + 0x8000u) >> 16);
}

// pack two f32 -> two bf16 in one dword. gfx950 has HW v_cvt_pk_bf16_f32.
#if __has_builtin(__builtin_amdgcn_cvt_pk_bf16_f32)
__device__ __forceinline__ u32 pk2(float lo, float hi) {
  auto r = __builtin_amdgcn_cvt_pk_bf16_f32(lo, hi);
  return __builtin_bit_cast(u32, r);
}
#else
__device__ __forceinline__ u32 pk2(float lo, float hi) {
  u32 a = __float_as_uint(lo) + 0x8000u;
  u32 b = __float_as_uint(hi) + 0x8000u;
  return __builtin_amdgcn_perm(b, a, 0x07060302);
}
#endif

// lane[i] <-> lane[i+32] exchange in one VALU op (T12).
#if __has_builtin(__builtin_amdgcn_permlane32_swap)
__device__ __forceinline__ void pswap(u32& a, u32& b) {
  auto r = __builtin_amdgcn_permlane32_swap(a, b, false, false);
  a = r[0]; b = r[1];
}
#else
__device__ __forceinline__ void pswap(u32& a, u32& b) {
  asm("v_permlane32_swap_b32 %0, %1" : "+v"(a), "+v"(b));
}
#endif

// convert 8 consecutive fp32 at src -> uint4 of 8 bf16 (pk2 rounding)
__device__ __forceinline__ uint4 cvt8(const float* __restrict__ src) {
  float4 a = *(const float4*)src;
  float4 b = *(const float4*)(src + 4);
  uint4 r;
  r.x = pk2(a.x, a.y); r.y = pk2(a.z, a.w);
  r.z = pk2(b.x, b.y); r.w = pk2(b.z, b.w);
  return r;
}

// ---------------------------------------------------------------------------
// Kernel A: QKV bf16 MFMA GEMM (R8 form: prep folded in, LDS V transpose).
// ---------------------------------------------------------------------------
__global__ __launch_bounds__(256) void qkv_kernel(
    const float* __restrict__ x, const float* __restrict__ qw,
    const float* __restrict__ bias, u16* __restrict__ Qb,
    u16* __restrict__ Kb, u16* __restrict__ Vb) {
  const int nt = blockIdx.x, bh = blockIdx.y;
  const int b = bh >> 3, h = bh & 7;
  const int tid = threadIdx.x;
  const int wid = tid >> 6, lane = tid & 63;
  const int r32 = lane & 31, hh = lane >> 5;
  const int n0 = nt * 128;

  // Ws/Xs live until MFMA done; Vt (128x136 u16 = 34.8KB) reuses the space.
  __shared__ __align__(16) union SH {
    struct { u16 Ws[192 * 72]; u16 Xs[128 * 72]; } s;
    u16 Vt[128 * 136];
  } sh;

  // stage W: inline fp32->bf16 conversion from qw[h] (prep folded in)
  const float* wqp = qw + (size_t)h * OQKV * 64;
  #pragma unroll
  for (int i = 0; i < 6; ++i) {
    int idx = i * 256 + tid;            // 0..1535 groups of 8
    int o = idx >> 3, c8 = (idx & 7) * 8;
    *(uint4*)&sh.s.Ws[o * 72 + c8] = cvt8(&wqp[o * 64 + c8]);
  }
  // stage X^T: two c-rows at a time, packed b32 stores
  const float* xp = x + ((size_t)b * DIM + h * 64) * Nn + n0;
  #pragma unroll
  for (int i = 0; i < 4; ++i) {
    int idx = i * 256 + tid;            // 0..1023
    int cp = idx >> 5, n4 = (idx & 31) * 4;
    const int c = 2 * cp;
    float4 a = *(const float4*)&xp[(size_t)c * Nn + n4];
    float4 d = *(const float4*)&xp[(size_t)(c + 1) * Nn + n4];
    *(u32*)&sh.s.Xs[(n4 + 0) * 72 + c] = pk2(a.x, d.x);
    *(u32*)&sh.s.Xs[(n4 + 1) * 72 + c] = pk2(a.y, d.y);
    *(u32*)&sh.s.Xs[(n4 + 2) * 72 + c] = pk2(a.z, d.z);
    *(u32*)&sh.s.Xs[(n4 + 3) * 72 + c] = pk2(a.w, d.w);
  }
  __syncthreads();

  f32x16 acc[6];
  #pragma unroll
  for (int t = 0; t < 6; ++t)
    #pragma unroll
    for (int r = 0; r < 16; ++r) acc[t][r] = 0.0f;

  const int nw = wid * 32;
  #pragma unroll
  for (int k = 0; k < 4; ++k) {
    const int ko = k * 16 + hh * 8;
    bf16x8 xb = *(const bf16x8*)&sh.s.Xs[(nw + r32) * 72 + ko];
    #pragma unroll
    for (int t = 0; t < 6; ++t) {
      bf16x8 wa = *(const bf16x8*)&sh.s.Ws[(t * 32 + r32) * 72 + ko];
      acc[t] = MFMA32(wa, xb, acc[t]);
    }
  }

  __syncthreads();  // all LDS reads done before Vt overwrites Ws/Xs

  const int nl = nw + r32;            // local n 0..127
  const int n = n0 + nl;
  const float* bp = bias + h * OQKV;
  #pragma unroll
  for (int t = 0; t < 6; ++t) {
    #pragma unroll
    for (int g = 0; g < 4; ++g) {
      const int ob = t * 32 + 8 * g + 4 * hh;
      float4 bv = *(const float4*)&bp[ob];
      float v0 = acc[t][4 * g + 0] + bv.x;
      float v1 = acc[t][4 * g + 1] + bv.y;
      float v2 = acc[t][4 * g + 2] + bv.z;
      float v3 = acc[t][4 * g + 3] + bv.w;
      if (t == 0) {                       // Q, scaled by SCALE*log2e
        uint2 pk;
        pk.x = pk2(v0 * SCALE2, v1 * SCALE2);
        pk.y = pk2(v2 * SCALE2, v3 * SCALE2);
        *(uint2*)&Qb[((size_t)bh * Nn + n) * 32 + ob] = pk;
      } else if (t == 1) {                // K (c = ob - 32)
        uint2 pk; pk.x = pk2(v0, v1); pk.y = pk2(v2, v3);
        *(uint2*)&Kb[((size_t)bh * Nn + n) * 32 + ob - 32] = pk;
      } else {                            // V (d = ob - 64) -> LDS transpose
        const int d = ob - 64;
        sh.Vt[(d + 0) * 136 + nl] = f2bf_rn(v0);
        sh.Vt[(d + 1) * 136 + nl] = f2bf_rn(v1);
        sh.Vt[(d + 2) * 136 + nl] = f2bf_rn(v2);
        sh.Vt[(d + 3) * 136 + nl] = f2bf_rn(v3);
      }
    }
  }
  __syncthreads();

  // cooperative V store: 8x b128 per thread, coalesced rows of [d][n]
  const int dd0 = tid >> 4;            // 0..15
  const int nn = (tid & 15) * 8;       // 0..120
  #pragma unroll
  for (int i = 0; i < 8; ++i) {
    const int dd = dd0 + i * 16;
    uint4 vv = *(const uint4*)&sh.Vt[dd * 136 + nn];
    *(uint4*)&Vb[((size_t)bh * DV + dd) * Nn + n0 + nn] = vv;
  }
}

// ---------------------------------------------------------------------------
// Kernel B: MFMA flash attention. R9: NO LDS, NO BARRIERS. V fragments are
// loaded per d-tile directly from global (L2-resident: 256KB/bh, 16 bh/XCD);
// identical addresses/values as the old LDS path -> bit-identical output.
// The per-chunk vmcnt(0)+s_barrier drain (the structural stall: pipe-time
// sum ~= wall time in R7) is gone; waves free-run, TLP hides load latency.
// S/PV software pipeline + permlane32 + setprio retained. K for the next S
// is loaded right after PV, with the ~150-op finishS tail covering latency.
// Explicit loop, no array-ref lambdas (R8 lesson).
// ---------------------------------------------------------------------------
__global__ __launch_bounds__(256) void attn_kernel(
    const u16* __restrict__ Qb, const u16* __restrict__ Kb,
    const u16* __restrict__ Vb, u16* __restrict__ Ot) {
  const int blk = blockIdx.x;            // 0..1023
  const int xcd = blk & 7, j = blk >> 3;
  const int bh = (xcd << 4) | (j >> 3);  // 16 bh per XCD
  const int mt = j & 7;
  const int tid = threadIdx.x;
  const int wid = tid >> 6, lane = tid & 63;
  const int r32 = lane & 31, hh = lane >> 5;
  const int mw = mt * 128 + wid * 32;

  const u16* qp = Qb + ((size_t)bh * Nn + mw + r32) * 32;
  const bf16x8 qb0 = *(const bf16x8*)&qp[hh * 8];
  const bf16x8 qb1 = *(const bf16x8*)&qp[16 + hh * 8];

  const u16* kbase = Kb + (size_t)bh * Nn * 32;
  // per-lane V pointer: row r32 (+t*32), col hh*8 (+ch*64 + s*16)
  const u16* vb = Vb + (size_t)bh * DV * Nn + (size_t)r32 * Nn + hh * 8;

  // K[0] frags -> S[0]
  bf16x8 ka[4];
  {
    const u16* kp0 = kbase + (size_t)r32 * 32;
    const u16* kp1 = kbase + (size_t)(32 + r32) * 32;
    ka[0] = *(const bf16x8*)&kp0[hh * 8];
    ka[1] = *(const bf16x8*)&kp0[16 + hh * 8];
    ka[2] = *(const bf16x8*)&kp1[hh * 8];
    ka[3] = *(const bf16x8*)&kp1[16 + hh * 8];
  }
  f32x16 c0, c1;
  #pragma unroll
  for (int r = 0; r < 16; ++r) { c0[r] = 0.0f; c1[r] = 0.0f; }
  c0 = MFMA32(ka[0], qb0, c0);
  c0 = MFMA32(ka[1], qb1, c0);
  c1 = MFMA32(ka[2], qb0, c1);
  c1 = MFMA32(ka[3], qb1, c1);

  // ka <- K[1] (consumed by iter 0's S[1])
  {
    const u16* kp0 = kbase + (size_t)(64 + r32) * 32;
    const u16* kp1 = kbase + (size_t)(96 + r32) * 32;
    ka[0] = *(const bf16x8*)&kp0[hh * 8];
    ka[1] = *(const bf16x8*)&kp0[16 + hh * 8];
    ka[2] = *(const bf16x8*)&kp1[hh * 8];
    ka[3] = *(const bf16x8*)&kp1[16 + hh * 8];
  }

  f32x16 o[4];                            // D[d][m], col m = r32
  #pragma unroll
  for (int t = 0; t < 4; ++t)
    #pragma unroll
    for (int r = 0; r < 16; ++r) o[t][r] = 0.0f;
  float lsum = 0.0f;
  u32 Pk[16];
  union { u32 d[4]; bf16x8 v; } pbf[4];

  // exp/sum/pack/swap of the S currently in c0,c1 -> pbf
  auto finishS = [&]() {
    float csum = 0.0f;
    #pragma unroll
    for (int r = 0; r < 16; ++r) { c0[r] = fexp2(c0[r]); csum += c0[r]; }
    #pragma unroll
    for (int r = 0; r < 16; ++r) { c1[r] = fexp2(c1[r]); csum += c1[r]; }
    lsum += csum;
    #pragma unroll
    for (int g = 0; g < 4; ++g) {
      Pk[2 * g]     = pk2(c0[4 * g + 0], c0[4 * g + 1]);
      Pk[2 * g + 1] = pk2(c0[4 * g + 2], c0[4 * g + 3]);
      Pk[8 + 2 * g]     = pk2(c1[4 * g + 0], c1[4 * g + 1]);
      Pk[8 + 2 * g + 1] = pk2(c1[4 * g + 2], c1[4 * g + 3]);
    }
    pswap(Pk[0], Pk[2]);   pswap(Pk[1], Pk[3]);
    pswap(Pk[4], Pk[6]);   pswap(Pk[5], Pk[7]);
    pswap(Pk[8], Pk[10]);  pswap(Pk[9], Pk[11]);
    pswap(Pk[12], Pk[14]); pswap(Pk[13], Pk[15]);
    #pragma unroll
    for (int i = 0; i < 4; ++i) {
      pbf[i].d[0] = Pk[4 * i + 0];
      pbf[i].d[1] = Pk[4 * i + 1];
      pbf[i].d[2] = Pk[4 * i + 2];
      pbf[i].d[3] = Pk[4 * i + 3];
    }
  };

  finishS();  // S[0] -> pbf

  for (int ch = 0; ch < 15; ++ch) {
    __builtin_amdgcn_s_setprio(1);
    // S[ch+1] from ka (loaded ~a finishS ago -> latency covered)
    #pragma unroll
    for (int r = 0; r < 16; ++r) { c0[r] = 0.0f; c1[r] = 0.0f; }
    c0 = MFMA32(ka[0], qb0, c0);
    c0 = MFMA32(ka[1], qb1, c0);
    c1 = MFMA32(ka[2], qb0, c1);
    c1 = MFMA32(ka[3], qb1, c1);

    // PV[ch]: per d-tile, 4 V-frag global loads (L2) + 4 MFMAs
    #pragma unroll
    for (int t = 0; t < 4; ++t) {
      const u16* vrow = vb + (size_t)(t * 32) * Nn + ch * 64;
      bf16x8 v0 = *(const bf16x8*)&vrow[0];
      bf16x8 v1 = *(const bf16x8*)&vrow[16];
      bf16x8 v2 = *(const bf16x8*)&vrow[32];
      bf16x8 v3 = *(const bf16x8*)&vrow[48];
      o[t] = MFMA32(v0, pbf[0].v, o[t]);
      o[t] = MFMA32(v1, pbf[1].v, o[t]);
      o[t] = MFMA32(v2, pbf[2].v, o[t]);
      o[t] = MFMA32(v3, pbf[3].v, o[t]);
    }
    __builtin_amdgcn_s_setprio(0);

    // load ka <- K[ch+2] (bh=127,ch=14 reads allocated Vb region; unused)
    {
      const u16* kp0 = kbase + (size_t)((ch + 2) * 64 + r32) * 32;
      const u16* kp1 = kbase + (size_t)((ch + 2) * 64 + 32 + r32) * 32;
      ka[0] = *(const bf16x8*)&kp0[hh * 8];
      ka[1] = *(const bf16x8*)&kp0[16 + hh * 8];
      ka[2] = *(const bf16x8*)&kp1[hh * 8];
      ka[3] = *(const bf16x8*)&kp1[16 + hh * 8];
    }

    // VALU tail: exp/pack/swap S[ch+1] while PV MFMAs drain; covers ka loads
    finishS();
  }

  // peeled chunk 15: PV only (pbf = S[15] packed in iter 14)
  __builtin_amdgcn_s_setprio(1);
  #pragma unroll
  for (int t = 0; t < 4; ++t) {
    const u16* vrow = vb + (size_t)(t * 32) * Nn + 15 * 64;
    bf16x8 v0 = *(const bf16x8*)&vrow[0];
    bf16x8 v1 = *(const bf16x8*)&vrow[16];
    bf16x8 v2 = *(const bf16x8*)&vrow[32];
    bf16x8 v3 = *(const bf16x8*)&vrow[48];
    o[t] = MFMA32(v0, pbf[0].v, o[t]);
    o[t] = MFMA32(v1, pbf[1].v, o[t]);
    o[t] = MFMA32(v2, pbf[2].v, o[t]);
    o[t] = MFMA32(v3, pbf[3].v, o[t]);
  }
  __builtin_amdgcn_s_setprio(0);

  lsum += __shfl_xor(lsum, 32, 64);
  const float inv = 1.0f / lsum;
  const int m = mw + r32;
  const int b = bh >> 3, h = bh & 7;
  u16* obase = Ot + ((size_t)b * Nn + m) * 1024 + h * DV + 4 * hh;
  #pragma unroll
  for (int t = 0; t < 4; ++t) {
    #pragma unroll
    for (int g = 0; g < 4; ++g) {
      float v0 = fmaxf(o[t][4 * g + 0] * inv, 0.0f);
      float v1 = fmaxf(o[t][4 * g + 1] * inv, 0.0f);
      float v2 = fmaxf(o[t][4 * g + 2] * inv, 0.0f);
      float v3 = fmaxf(o[t][4 * g + 3] * inv, 0.0f);
      uint2 pk; pk.x = pk2(v0, v1); pk.y = pk2(v2, v3);
      *(uint2*)&obase[t * 32 + 8 * g] = pk;
    }
  }
}

// ---------------------------------------------------------------------------
// Kernel C: proj bf16 MFMA GEMM, R2-passing 2-phase structure, prep folded
// in (R8 form).
// ---------------------------------------------------------------------------
__global__ __launch_bounds__(256) void proj_kernel(
    const u16* __restrict__ Ot, const float* __restrict__ pw,
    const float* __restrict__ pb, const float* __restrict__ g,
    const float* __restrict__ bt, const float* __restrict__ mn,
    const float* __restrict__ vr, float* __restrict__ out) {
  const int blk = blockIdx.x;               // 0..511
  const int xcd = blk & 7, rr = blk >> 3;   // 64 blocks per XCD
  const int pairl = rr >> 2, oct = rr & 3;  // 16 (b,n0) pairs per XCD
  const int pair = xcd * 16 + pairl;        // 0..127
  const int b = pair >> 3, nt = pair & 7;
  const int n0 = nt * 128, oc0 = oct * 128;
  const int tid = threadIdx.x;
  const int wid = tid >> 6, lane = tid & 63;
  const int r32 = lane & 31, hh = lane >> 5;
  const int ocw = (wid >> 1) * 64, nw = (wid & 1) * 64;

  __shared__ __align__(16) u16 Ws[128 * 72];  // [oc][64 ic]
  __shared__ __align__(16) u16 Os[128 * 72];  // [n][64 ic]
  __shared__ __align__(16) float invL[128];   // BN fold, block's oc slice
  __shared__ __align__(16) float addL[128];

  // BN+bias fold for this block's 128 output channels (prep folded in)
  if (tid < 128) {
    const int oc = oc0 + tid;
    float inv = g[oc] * rsqrtf(vr[oc] + 1e-5f);
    invL[tid] = inv;
    addL[tid] = pb[oc] * inv + bt[oc] - mn[oc] * inv;
  }

  f32x16 o[2][2];
  #pragma unroll
  for (int t = 0; t < 2; ++t)
    #pragma unroll
    for (int u = 0; u < 2; ++u)
      #pragma unroll
      for (int r = 0; r < 16; ++r) o[t][u][r] = 0.0f;

  for (int ic0 = 0; ic0 < 1024; ic0 += 64) {
    __syncthreads();
    #pragma unroll
    for (int i = 0; i < 4; ++i) {       // stage W: 128x64, fp32->bf16 inline
      int idx = i * 256 + tid;          // 0..1023
      int row = idx >> 3, c8 = (idx & 7) * 8;
      *(uint4*)&Ws[row * 72 + c8] =
          cvt8(&pw[(size_t)(oc0 + row) * 1024 + ic0 + c8]);
    }
    #pragma unroll
    for (int i = 0; i < 4; ++i) {       // stage Ot: 128x64 bf16, b128 copies
      int idx = i * 256 + tid;
      int row = idx >> 3, c8 = (idx & 7) * 8;
      *(uint4*)&Os[row * 72 + c8] =
          *(const uint4*)&Ot[((size_t)b * Nn + n0 + row) * 1024 + ic0 + c8];
    }
    __syncthreads();

    #pragma unroll
    for (int s = 0; s < 4; ++s) {
      const int ko = s * 16 + hh * 8;
      bf16x8 a0 = *(const bf16x8*)&Ws[(ocw + r32) * 72 + ko];
      bf16x8 a1 = *(const bf16x8*)&Ws[(ocw + 32 + r32) * 72 + ko];
      bf16x8 b0 = *(const bf16x8*)&Os[(nw + r32) * 72 + ko];
      bf16x8 b1 = *(const bf16x8*)&Os[(nw + 32 + r32) * 72 + ko];
      o[0][0] = MFMA32(a0, b0, o[0][0]);
      o[0][1] = MFMA32(a0, b1, o[0][1]);
      o[1][0] = MFMA32(a1, b0, o[1][0]);
      o[1][1] = MFMA32(a1, b1, o[1][1]);
    }
  }

  #pragma unroll
  for (int t = 0; t < 2; ++t) {
    const int lbase = ocw + t * 32 + 4 * hh;   // oc - oc0
    #pragma unroll
    for (int g = 0; g < 4; ++g) {
      const int l = lbase + 8 * g;
      const int oc = oc0 + l;
      float4 iv = *(const float4*)&invL[l];
      float4 av = *(const float4*)&addL[l];
      #pragma unroll
      for (int u = 0; u < 2; ++u) {
        const int n = n0 + nw + u * 32 + r32;
        out[((size_t)b * DIM + oc + 0) * Nn + n] = o[t][u][4 * g + 0] * iv.x + av.x;
        out[((size_t)b * DIM + oc + 1) * Nn + n] = o[t][u][4 * g + 1] * iv.y + av.y;
        out[((size_t)b * DIM + oc + 2) * Nn + n] = o[t][u][4 * g + 2] * iv.z + av.z;
        out[((size_t)b * DIM + oc + 3) * Nn + n] = o[t][u][4 * g + 3] * iv.w + av.w;
      }
    }
  }
}

// ---------------------------------------------------------------------------
extern "C" void kernel_launch(void* const* d_in, const int* in_sizes, int n_in,
                              void* d_out, int out_size, void* d_ws,
                              size_t ws_size, hipStream_t stream) {
  const float* x      = (const float*)d_in[0];
  const float* qkv_w  = (const float*)d_in[1];
  const float* qkv_b  = (const float*)d_in[2];
  const float* proj_w = (const float*)d_in[3];
  const float* proj_b = (const float*)d_in[4];
  const float* bn_g   = (const float*)d_in[5];
  const float* bn_b   = (const float*)d_in[6];
  const float* bn_m   = (const float*)d_in[7];
  const float* bn_v   = (const float*)d_in[8];
  float* out = (float*)d_out;

  char* ws = (char*)d_ws;
  u16* Qb   = (u16*)(ws);                 // 8 MB
  u16* Kb   = (u16*)(ws + 8388608);       // 8 MB
  u16* Vb   = (u16*)(ws + 16777216);      // 32 MB (+slack)
  u16* Ot   = (u16*)(ws + 50331648);      // 32 MB [b][m][ic]

  qkv_kernel<<<dim3(8, Bb * Hh), 256, 0, stream>>>(x, qkv_w, qkv_b, Qb, Kb, Vb);
  attn_kernel<<<dim3(1024), 256, 0, stream>>>(Qb, Kb, Vb, Ot);
  proj_kernel<<<dim3(512), 256, 0, stream>>>(Ot, proj_w, proj_b, bn_g, bn_b,
                                             bn_m, bn_v, out);
}

// Round 10
// 189.132 us; speedup vs baseline: 1.5854x; 1.5854x over previous
//
#include <hip/hip_runtime.h>
#include <math.h>

typedef unsigned short u16;
typedef unsigned int u32;

#define Bb   16
#define Hh   8
#define KD   32
#define DV   128
#define DIM  512
#define Nn   1024
#define OQKV 192
// SCALE * log2(e): QK logits in log2-domain; softmax exp -> v_exp_f32 (2^x)
#define SCALE2 0.25503490221320355f

typedef short bf16x8 __attribute__((ext_vector_type(8)));   // 4 VGPRs = 8 bf16
typedef float f32x16 __attribute__((ext_vector_type(16)));  // 32x32 C/D frag

#define MFMA32(a, b, c) __builtin_amdgcn_mfma_f32_32x32x16_bf16(a, b, c, 0, 0, 0)

__device__ __forceinline__ float fexp2(float x) {
#if __has_builtin(__builtin_amdgcn_exp2f)
  return __builtin_amdgcn_exp2f(x);
#else
  return exp2f(x);
#endif
}

__device__ __forceinline__ u16 f2bf_rn(float f) {
  return (u16)((__float_as_uint(f) + 0x8000u) >> 16);
}

// pack two f32 -> two bf16 in one dword. gfx950 has HW v_cvt_pk_bf16_f32.
#if __has_builtin(__builtin_amdgcn_cvt_pk_bf16_f32)
__device__ __forceinline__ u32 pk2(float lo, float hi) {
  auto r = __builtin_amdgcn_cvt_pk_bf16_f32(lo, hi);
  return __builtin_bit_cast(u32, r);
}
#else
__device__ __forceinline__ u32 pk2(float lo, float hi) {
  u32 a = __float_as_uint(lo) + 0x8000u;
  u32 b = __float_as_uint(hi) + 0x8000u;
  return __builtin_amdgcn_perm(b, a, 0x07060302);
}
#endif

// lane[i] <-> lane[i+32] exchange in one VALU op (T12).
#if __has_builtin(__builtin_amdgcn_permlane32_swap)
__device__ __forceinline__ void pswap(u32& a, u32& b) {
  auto r = __builtin_amdgcn_permlane32_swap(a, b, false, false);
  a = r[0]; b = r[1];
}
#else
__device__ __forceinline__ void pswap(u32& a, u32& b) {
  asm("v_permlane32_swap_b32 %0, %1" : "+v"(a), "+v"(b));
}
#endif

// convert 8 consecutive fp32 at src -> uint4 of 8 bf16 (pk2 rounding)
__device__ __forceinline__ uint4 cvt8(const float* __restrict__ src) {
  float4 a = *(const float4*)src;
  float4 b = *(const float4*)(src + 4);
  uint4 r;
  r.x = pk2(a.x, a.y); r.y = pk2(a.z, a.w);
  r.z = pk2(b.x, b.y); r.w = pk2(b.z, b.w);
  return r;
}

// ---------------------------------------------------------------------------
// Kernel A: QKV bf16 MFMA GEMM. R10: Q and K now also exit via LDS (Qs/Ks
// 8KB each in the epilogue union) -> 32B/thread fully-coalesced stores,
// replacing 8B uint2 stores at 64B stride (each 64B line was written by 4
// separate instructions). Values bit-identical. Union 45->50KB, still 3
// blocks/CU.
// ---------------------------------------------------------------------------
__global__ __launch_bounds__(256) void qkv_kernel(
    const float* __restrict__ x, const float* __restrict__ qw,
    const float* __restrict__ bias, u16* __restrict__ Qb,
    u16* __restrict__ Kb, u16* __restrict__ Vb) {
  const int nt = blockIdx.x, bh = blockIdx.y;
  const int b = bh >> 3, h = bh & 7;
  const int tid = threadIdx.x;
  const int wid = tid >> 6, lane = tid & 63;
  const int r32 = lane & 31, hh = lane >> 5;
  const int n0 = nt * 128;

  // stage (45KB) lives until MFMA done; out (50KB) reuses the space.
  __shared__ __align__(16) union SH {
    struct { u16 Ws[192 * 72]; u16 Xs[128 * 72]; } s;
    struct { u16 Vt[128 * 136]; u16 Qs[128 * 32]; u16 Ks[128 * 32]; } o;
  } sh;

  // stage W: inline fp32->bf16 conversion from qw[h] (prep folded in)
  const float* wqp = qw + (size_t)h * OQKV * 64;
  #pragma unroll
  for (int i = 0; i < 6; ++i) {
    int idx = i * 256 + tid;            // 0..1535 groups of 8
    int o = idx >> 3, c8 = (idx & 7) * 8;
    *(uint4*)&sh.s.Ws[o * 72 + c8] = cvt8(&wqp[o * 64 + c8]);
  }
  // stage X^T: two c-rows at a time, packed b32 stores
  const float* xp = x + ((size_t)b * DIM + h * 64) * Nn + n0;
  #pragma unroll
  for (int i = 0; i < 4; ++i) {
    int idx = i * 256 + tid;            // 0..1023
    int cp = idx >> 5, n4 = (idx & 31) * 4;
    const int c = 2 * cp;
    float4 a = *(const float4*)&xp[(size_t)c * Nn + n4];
    float4 d = *(const float4*)&xp[(size_t)(c + 1) * Nn + n4];
    *(u32*)&sh.s.Xs[(n4 + 0) * 72 + c] = pk2(a.x, d.x);
    *(u32*)&sh.s.Xs[(n4 + 1) * 72 + c] = pk2(a.y, d.y);
    *(u32*)&sh.s.Xs[(n4 + 2) * 72 + c] = pk2(a.z, d.z);
    *(u32*)&sh.s.Xs[(n4 + 3) * 72 + c] = pk2(a.w, d.w);
  }
  __syncthreads();

  f32x16 acc[6];
  #pragma unroll
  for (int t = 0; t < 6; ++t)
    #pragma unroll
    for (int r = 0; r < 16; ++r) acc[t][r] = 0.0f;

  const int nw = wid * 32;
  #pragma unroll
  for (int k = 0; k < 4; ++k) {
    const int ko = k * 16 + hh * 8;
    bf16x8 xb = *(const bf16x8*)&sh.s.Xs[(nw + r32) * 72 + ko];
    #pragma unroll
    for (int t = 0; t < 6; ++t) {
      bf16x8 wa = *(const bf16x8*)&sh.s.Ws[(t * 32 + r32) * 72 + ko];
      acc[t] = MFMA32(wa, xb, acc[t]);
    }
  }

  __syncthreads();  // all LDS reads done before epilogue overwrites Ws/Xs

  const int nl = nw + r32;            // local n 0..127
  const float* bp = bias + h * OQKV;
  #pragma unroll
  for (int t = 0; t < 6; ++t) {
    #pragma unroll
    for (int g = 0; g < 4; ++g) {
      const int ob = t * 32 + 8 * g + 4 * hh;
      float4 bv = *(const float4*)&bp[ob];
      float v0 = acc[t][4 * g + 0] + bv.x;
      float v1 = acc[t][4 * g + 1] + bv.y;
      float v2 = acc[t][4 * g + 2] + bv.z;
      float v3 = acc[t][4 * g + 3] + bv.w;
      if (t == 0) {                       // Q (scaled) -> LDS
        uint2 pk;
        pk.x = pk2(v0 * SCALE2, v1 * SCALE2);
        pk.y = pk2(v2 * SCALE2, v3 * SCALE2);
        *(uint2*)&sh.o.Qs[nl * 32 + ob] = pk;
      } else if (t == 1) {                // K -> LDS (c = ob - 32)
        uint2 pk; pk.x = pk2(v0, v1); pk.y = pk2(v2, v3);
        *(uint2*)&sh.o.Ks[nl * 32 + ob - 32] = pk;
      } else {                            // V (d = ob - 64) -> LDS transpose
        const int d = ob - 64;
        sh.o.Vt[(d + 0) * 136 + nl] = f2bf_rn(v0);
        sh.o.Vt[(d + 1) * 136 + nl] = f2bf_rn(v1);
        sh.o.Vt[(d + 2) * 136 + nl] = f2bf_rn(v2);
        sh.o.Vt[(d + 3) * 136 + nl] = f2bf_rn(v3);
      }
    }
  }
  __syncthreads();

  // coalesced stores: V 8x b128 rows of [d][n]; Q/K 32B/thread contiguous
  const int dd0 = tid >> 4;            // 0..15
  const int nn = (tid & 15) * 8;       // 0..120
  #pragma unroll
  for (int i = 0; i < 8; ++i) {
    const int dd = dd0 + i * 16;
    uint4 vv = *(const uint4*)&sh.o.Vt[dd * 136 + nn];
    *(uint4*)&Vb[((size_t)bh * DV + dd) * Nn + n0 + nn] = vv;
  }
  {
    const size_t base = ((size_t)bh * Nn + n0) * 32;   // u16 units
    uint4 q0 = *(const uint4*)&sh.o.Qs[tid * 16];
    uint4 q1 = *(const uint4*)&sh.o.Qs[tid * 16 + 8];
    *(uint4*)&Qb[base + tid * 16] = q0;
    *(uint4*)&Qb[base + tid * 16 + 8] = q1;
    uint4 k0 = *(const uint4*)&sh.o.Ks[tid * 16];
    uint4 k1 = *(const uint4*)&sh.o.Ks[tid * 16 + 8];
    *(uint4*)&Kb[base + tid * 16] = k0;
    *(uint4*)&Kb[base + tid * 16 + 8] = k1;
  }
}

// ---------------------------------------------------------------------------
// Kernel B: MFMA flash attention — R7-exact (best measured: 66.0us).
// LDS V double-buffer + per-chunk barrier (R9 proved direct global V loads
// are an uncoalesced-gather disaster); S/PV software pipeline, permlane32
// half-exchange, setprio. Explicit loop, explicit kn->ka copy.
// ---------------------------------------------------------------------------
__global__ __launch_bounds__(256) void attn_kernel(
    const u16* __restrict__ Qb, const u16* __restrict__ Kb,
    const u16* __restrict__ Vb, u16* __restrict__ Ot) {
  const int blk = blockIdx.x;            // 0..1023
  const int xcd = blk & 7, j = blk >> 3;
  const int bh = (xcd << 4) | (j >> 3);  // 16 bh per XCD
  const int mt = j & 7;
  const int tid = threadIdx.x;
  const int wid = tid >> 6, lane = tid & 63;
  const int r32 = lane & 31, hh = lane >> 5;
  const int mw = mt * 128 + wid * 32;

  __shared__ __align__(16) u16 Vs[2][128 * 72];  // [d][64n], pad 72

  const u16* qp = Qb + ((size_t)bh * Nn + mw + r32) * 32;
  const bf16x8 qb0 = *(const bf16x8*)&qp[hh * 8];
  const bf16x8 qb1 = *(const bf16x8*)&qp[16 + hh * 8];

  const u16* kbase = Kb + (size_t)bh * Nn * 32;
  const u16* vbase = Vb + (size_t)bh * DV * Nn;

  int sd[4], sn[4];
  #pragma unroll
  for (int i = 0; i < 4; ++i) {
    int idx = i * 256 + tid;
    sd[i] = idx >> 3; sn[i] = (idx & 7) * 8;
  }

  // prologue: stage V chunk 0
  uint4 vreg[4];
  #pragma unroll
  for (int i = 0; i < 4; ++i)
    vreg[i] = *(const uint4*)&vbase[(size_t)sd[i] * Nn + sn[i]];
  #pragma unroll
  for (int i = 0; i < 4; ++i)
    *(uint4*)&Vs[0][sd[i] * 72 + sn[i]] = vreg[i];

  // K[0] frags -> S[0]
  bf16x8 ka[4];
  {
    const u16* kp0 = kbase + (size_t)r32 * 32;
    const u16* kp1 = kbase + (size_t)(32 + r32) * 32;
    ka[0] = *(const bf16x8*)&kp0[hh * 8];
    ka[1] = *(const bf16x8*)&kp0[16 + hh * 8];
    ka[2] = *(const bf16x8*)&kp1[hh * 8];
    ka[3] = *(const bf16x8*)&kp1[16 + hh * 8];
  }
  f32x16 c0, c1;
  #pragma unroll
  for (int r = 0; r < 16; ++r) { c0[r] = 0.0f; c1[r] = 0.0f; }
  c0 = MFMA32(ka[0], qb0, c0);
  c0 = MFMA32(ka[1], qb1, c0);
  c1 = MFMA32(ka[2], qb0, c1);
  c1 = MFMA32(ka[3], qb1, c1);

  // ka <- K[1] (consumed by iter 0's S[1])
  {
    const u16* kp0 = kbase + (size_t)(64 + r32) * 32;
    const u16* kp1 = kbase + (size_t)(96 + r32) * 32;
    ka[0] = *(const bf16x8*)&kp0[hh * 8];
    ka[1] = *(const bf16x8*)&kp0[16 + hh * 8];
    ka[2] = *(const bf16x8*)&kp1[hh * 8];
    ka[3] = *(const bf16x8*)&kp1[16 + hh * 8];
  }

  f32x16 o[4];                            // D[d][m], col m = r32
  #pragma unroll
  for (int t = 0; t < 4; ++t)
    #pragma unroll
    for (int r = 0; r < 16; ++r) o[t][r] = 0.0f;
  float lsum = 0.0f;
  u32 Pk[16];
  union { u32 d[4]; bf16x8 v; } pbf[4];

  // exp/sum/pack/swap of the S currently in c0,c1 -> pbf
  auto finishS = [&]() {
    float csum = 0.0f;
    #pragma unroll
    for (int r = 0; r < 16; ++r) { c0[r] = fexp2(c0[r]); csum += c0[r]; }
    #pragma unroll
    for (int r = 0; r < 16; ++r) { c1[r] = fexp2(c1[r]); csum += c1[r]; }
    lsum += csum;
    #pragma unroll
    for (int g = 0; g < 4; ++g) {
      Pk[2 * g]     = pk2(c0[4 * g + 0], c0[4 * g + 1]);
      Pk[2 * g + 1] = pk2(c0[4 * g + 2], c0[4 * g + 3]);
      Pk[8 + 2 * g]     = pk2(c1[4 * g + 0], c1[4 * g + 1]);
      Pk[8 + 2 * g + 1] = pk2(c1[4 * g + 2], c1[4 * g + 3]);
    }
    pswap(Pk[0], Pk[2]);   pswap(Pk[1], Pk[3]);
    pswap(Pk[4], Pk[6]);   pswap(Pk[5], Pk[7]);
    pswap(Pk[8], Pk[10]);  pswap(Pk[9], Pk[11]);
    pswap(Pk[12], Pk[14]); pswap(Pk[13], Pk[15]);
    #pragma unroll
    for (int i = 0; i < 4; ++i) {
      pbf[i].d[0] = Pk[4 * i + 0];
      pbf[i].d[1] = Pk[4 * i + 1];
      pbf[i].d[2] = Pk[4 * i + 2];
      pbf[i].d[3] = Pk[4 * i + 3];
    }
  };

  finishS();  // S[0] -> pbf

  for (int ch = 0; ch < 15; ++ch) {
    const int p = ch & 1;
    __syncthreads();  // Vs[p] writes visible; Vs[1-p] readers done

    // prefetch V[ch+1] (lands during the MFMA cluster below)
    #pragma unroll
    for (int i = 0; i < 4; ++i)
      vreg[i] = *(const uint4*)&vbase[(size_t)sd[i] * Nn + (ch + 1) * 64 + sn[i]];

    __builtin_amdgcn_s_setprio(1);
    // S[ch+1] from ka (prefetched one iter ago -> no load stall)
    #pragma unroll
    for (int r = 0; r < 16; ++r) { c0[r] = 0.0f; c1[r] = 0.0f; }
    c0 = MFMA32(ka[0], qb0, c0);
    c0 = MFMA32(ka[1], qb1, c0);
    c1 = MFMA32(ka[2], qb0, c1);
    c1 = MFMA32(ka[3], qb1, c1);

    // issue K[ch+2] loads (ch=14 reads workspace slack; value unused)
    bf16x8 kn[4];
    {
      const u16* kp0 = kbase + (size_t)((ch + 2) * 64 + r32) * 32;
      const u16* kp1 = kbase + (size_t)((ch + 2) * 64 + 32 + r32) * 32;
      kn[0] = *(const bf16x8*)&kp0[hh * 8];
      kn[1] = *(const bf16x8*)&kp0[16 + hh * 8];
      kn[2] = *(const bf16x8*)&kp1[hh * 8];
      kn[3] = *(const bf16x8*)&kp1[16 + hh * 8];
    }

    // PV[ch]: pbf was packed last iter. O[d][m] += V x P, 4 d-tiles x 4 k.
    #pragma unroll
    for (int t = 0; t < 4; ++t) {
      const u16* vrow = &Vs[p][(t * 32 + r32) * 72];
      #pragma unroll
      for (int s = 0; s < 4; ++s) {
        bf16x8 va = *(const bf16x8*)&vrow[s * 16 + hh * 8];
        o[t] = MFMA32(va, pbf[s].v, o[t]);
      }
    }
    __builtin_amdgcn_s_setprio(0);

    // park staged V regs into the other buffer
    #pragma unroll
    for (int i = 0; i < 4; ++i)
      *(uint4*)&Vs[1 - p][sd[i] * 72 + sn[i]] = vreg[i];

    // VALU tail: exp/pack/swap S[ch+1] while PV MFMAs drain
    finishS();

    #pragma unroll
    for (int i = 0; i < 4; ++i) ka[i] = kn[i];
  }

  // peeled chunk 15: PV only (pbf = S[15] packed in iter 14)
  __syncthreads();
  __builtin_amdgcn_s_setprio(1);
  #pragma unroll
  for (int t = 0; t < 4; ++t) {
    const u16* vrow = &Vs[1][(t * 32 + r32) * 72];
    #pragma unroll
    for (int s = 0; s < 4; ++s) {
      bf16x8 va = *(const bf16x8*)&vrow[s * 16 + hh * 8];
      o[t] = MFMA32(va, pbf[s].v, o[t]);
    }
  }
  __builtin_amdgcn_s_setprio(0);

  lsum += __shfl_xor(lsum, 32, 64);
  const float inv = 1.0f / lsum;
  const int m = mw + r32;
  const int b = bh >> 3, h = bh & 7;
  u16* obase = Ot + ((size_t)b * Nn + m) * 1024 + h * DV + 4 * hh;
  #pragma unroll
  for (int t = 0; t < 4; ++t) {
    #pragma unroll
    for (int g = 0; g < 4; ++g) {
      float v0 = fmaxf(o[t][4 * g + 0] * inv, 0.0f);
      float v1 = fmaxf(o[t][4 * g + 1] * inv, 0.0f);
      float v2 = fmaxf(o[t][4 * g + 2] * inv, 0.0f);
      float v3 = fmaxf(o[t][4 * g + 3] * inv, 0.0f);
      uint2 pk; pk.x = pk2(v0, v1); pk.y = pk2(v2, v3);
      *(uint2*)&obase[t * 32 + 8 * g] = pk;
    }
  }
}

// ---------------------------------------------------------------------------
// Kernel C: proj bf16 MFMA GEMM, R2-passing 2-phase structure, prep folded
// in (R8 form).
// ---------------------------------------------------------------------------
__global__ __launch_bounds__(256) void proj_kernel(
    const u16* __restrict__ Ot, const float* __restrict__ pw,
    const float* __restrict__ pb, const float* __restrict__ g,
    const float* __restrict__ bt, const float* __restrict__ mn,
    const float* __restrict__ vr, float* __restrict__ out) {
  const int blk = blockIdx.x;               // 0..511
  const int xcd = blk & 7, rr = blk >> 3;   // 64 blocks per XCD
  const int pairl = rr >> 2, oct = rr & 3;  // 16 (b,n0) pairs per XCD
  const int pair = xcd * 16 + pairl;        // 0..127
  const int b = pair >> 3, nt = pair & 7;
  const int n0 = nt * 128, oc0 = oct * 128;
  const int tid = threadIdx.x;
  const int wid = tid >> 6, lane = tid & 63;
  const int r32 = lane & 31, hh = lane >> 5;
  const int ocw = (wid >> 1) * 64, nw = (wid & 1) * 64;

  __shared__ __align__(16) u16 Ws[128 * 72];  // [oc][64 ic]
  __shared__ __align__(16) u16 Os[128 * 72];  // [n][64 ic]
  __shared__ __align__(16) float invL[128];   // BN fold, block's oc slice
  __shared__ __align__(16) float addL[128];

  // BN+bias fold for this block's 128 output channels (prep folded in)
  if (tid < 128) {
    const int oc = oc0 + tid;
    float inv = g[oc] * rsqrtf(vr[oc] + 1e-5f);
    invL[tid] = inv;
    addL[tid] = pb[oc] * inv + bt[oc] - mn[oc] * inv;
  }

  f32x16 o[2][2];
  #pragma unroll
  for (int t = 0; t < 2; ++t)
    #pragma unroll
    for (int u = 0; u < 2; ++u)
      #pragma unroll
      for (int r = 0; r < 16; ++r) o[t][u][r] = 0.0f;

  for (int ic0 = 0; ic0 < 1024; ic0 += 64) {
    __syncthreads();
    #pragma unroll
    for (int i = 0; i < 4; ++i) {       // stage W: 128x64, fp32->bf16 inline
      int idx = i * 256 + tid;          // 0..1023
      int row = idx >> 3, c8 = (idx & 7) * 8;
      *(uint4*)&Ws[row * 72 + c8] =
          cvt8(&pw[(size_t)(oc0 + row) * 1024 + ic0 + c8]);
    }
    #pragma unroll
    for (int i = 0; i < 4; ++i) {       // stage Ot: 128x64 bf16, b128 copies
      int idx = i * 256 + tid;
      int row = idx >> 3, c8 = (idx & 7) * 8;
      *(uint4*)&Os[row * 72 + c8] =
          *(const uint4*)&Ot[((size_t)b * Nn + n0 + row) * 1024 + ic0 + c8];
    }
    __syncthreads();

    #pragma unroll
    for (int s = 0; s < 4; ++s) {
      const int ko = s * 16 + hh * 8;
      bf16x8 a0 = *(const bf16x8*)&Ws[(ocw + r32) * 72 + ko];
      bf16x8 a1 = *(const bf16x8*)&Ws[(ocw + 32 + r32) * 72 + ko];
      bf16x8 b0 = *(const bf16x8*)&Os[(nw + r32) * 72 + ko];
      bf16x8 b1 = *(const bf16x8*)&Os[(nw + 32 + r32) * 72 + ko];
      o[0][0] = MFMA32(a0, b0, o[0][0]);
      o[0][1] = MFMA32(a0, b1, o[0][1]);
      o[1][0] = MFMA32(a1, b0, o[1][0]);
      o[1][1] = MFMA32(a1, b1, o[1][1]);
    }
  }

  #pragma unroll
  for (int t = 0; t < 2; ++t) {
    const int lbase = ocw + t * 32 + 4 * hh;   // oc - oc0
    #pragma unroll
    for (int g = 0; g < 4; ++g) {
      const int l = lbase + 8 * g;
      const int oc = oc0 + l;
      float4 iv = *(const float4*)&invL[l];
      float4 av = *(const float4*)&addL[l];
      #pragma unroll
      for (int u = 0; u < 2; ++u) {
        const int n = n0 + nw + u * 32 + r32;
        out[((size_t)b * DIM + oc + 0) * Nn + n] = o[t][u][4 * g + 0] * iv.x + av.x;
        out[((size_t)b * DIM + oc + 1) * Nn + n] = o[t][u][4 * g + 1] * iv.y + av.y;
        out[((size_t)b * DIM + oc + 2) * Nn + n] = o[t][u][4 * g + 2] * iv.z + av.z;
        out[((size_t)b * DIM + oc + 3) * Nn + n] = o[t][u][4 * g + 3] * iv.w + av.w;
      }
    }
  }
}

// ---------------------------------------------------------------------------
extern "C" void kernel_launch(void* const* d_in, const int* in_sizes, int n_in,
                              void* d_out, int out_size, void* d_ws,
                              size_t ws_size, hipStream_t stream) {
  const float* x      = (const float*)d_in[0];
  const float* qkv_w  = (const float*)d_in[1];
  const float* qkv_b  = (const float*)d_in[2];
  const float* proj_w = (const float*)d_in[3];
  const float* proj_b = (const float*)d_in[4];
  const float* bn_g   = (const float*)d_in[5];
  const float* bn_b   = (const float*)d_in[6];
  const float* bn_m   = (const float*)d_in[7];
  const float* bn_v   = (const float*)d_in[8];
  float* out = (float*)d_out;

  char* ws = (char*)d_ws;
  u16* Qb   = (u16*)(ws);                 // 8 MB
  u16* Kb   = (u16*)(ws + 8388608);       // 8 MB
  u16* Vb   = (u16*)(ws + 16777216);      // 32 MB (+slack)
  u16* Ot   = (u16*)(ws + 50331648);      // 32 MB [b][m][ic]

  qkv_kernel<<<dim3(8, Bb * Hh), 256, 0, stream>>>(x, qkv_w, qkv_b, Qb, Kb, Vb);
  attn_kernel<<<dim3(1024), 256, 0, stream>>>(Qb, Kb, Vb, Ot);
  proj_kernel<<<dim3(512), 256, 0, stream>>>(Ot, proj_w, proj_b, bn_g, bn_b,
                                             bn_m, bn_v, out);
}